// Round 1
// baseline (11270.894 us; speedup 1.0000x reference)
//
#include <hip/hip_runtime.h>

typedef _Float16 half8 __attribute__((ext_vector_type(8)));
typedef float f32x4 __attribute__((ext_vector_type(4)));

#define NWAVE 8
#define TPB 512

__device__ __forceinline__ float sigmoidf_(float x) {
    return 1.0f / (1.0f + __expf(-x));
}
__device__ __forceinline__ float tanhf_(float x) {
    // tanh(x) = 1 - 2/(1+e^{2x}); robust for large |x| (inf -> 1, 0 -> -1)
    return 1.0f - 2.0f / (1.0f + __expf(2.0f * x));
}

// Column of the gate matrix owned by (wave w, tile n, lane-col lc):
// gate q = n>>1 (i,f,g,o), sub-halftile s = n&1, h-index j = 32w + 16s + lc
__device__ __forceinline__ int col0_of(int w, int n) {
    return 256 * (n >> 1) + 32 * w + 16 * (n & 1);
}

// ---------------------------------------------------------------------------
// PREP: build fp16 B-fragment tables for U1,U2.
// Layout: Uf[w][n][kk][lane] : half8, frag b[j] = U[kk*32 + (l>>4)*8 + j][col0+ (l&15)]
// ---------------------------------------------------------------------------
__global__ void prep_kernel(const float* __restrict__ U1, const float* __restrict__ U2,
                            half8* __restrict__ U1f, half8* __restrict__ U2f) {
    int id = blockIdx.x * 512 + threadIdx.x;  // 0..32767
    int l  = id & 63;
    int kk = (id >> 6) & 7;
    int n  = (id >> 9) & 7;
    int w  = (id >> 12) & 7;
    int col = col0_of(w, n) + (l & 15);
    int k0  = kk * 32 + (l >> 4) * 8;
    half8 a, b;
#pragma unroll
    for (int j = 0; j < 8; ++j) {
        a[j] = (_Float16)U1[(k0 + j) * 1024 + col];
        b[j] = (_Float16)U2[(k0 + j) * 1024 + col];
    }
    U1f[id] = a;
    U2f[id] = b;
}

// ---------------------------------------------------------------------------
// GEMM_XW (fp32 VALU, exact): xw[tl][g][w][n][lane] (f32x4, C-fragment layout)
//   layer1 (K=128): A = x[b][t][f], rows b=16g+row, t = t0 + tlb*4 + tp
//   layer2 (K=256): A = h1c[tl][g][row][k]
// Adds bias. Grid: (TC/4)*8 blocks of 512 threads.
// ---------------------------------------------------------------------------
template <int K>
__global__ __launch_bounds__(512, 2)
void gemm_xw(const float* __restrict__ A, const float* __restrict__ W,
             const float* __restrict__ bias, f32x4* __restrict__ xw, int t0) {
    __shared__ float a_lds[4][K][16];  // [tp][k][row] (transposed for f32x4 row reads)
    int bid = blockIdx.x;
    int tlb = bid >> 3, g = bid & 7;
    int tid = threadIdx.x;

    if constexpr (K == 128) {
        // layer 1: x is [128][1024][128]
        int pair = tid >> 3, fs = tid & 7;
        int tp = pair >> 4, row = pair & 15;
        const float* src = A + ((size_t)(16 * g + row) * 1024 + (t0 + tlb * 4 + tp)) * 128 + fs * 16;
#pragma unroll
        for (int j = 0; j < 16; ++j) a_lds[tp][fs * 16 + j][row] = src[j];
    } else {
        // layer 2: h1c is [TC][8][16][256]
        int pair = tid >> 3, ks = tid & 7;
        int tp = pair >> 4, row = pair & 15;
        const float* src = A + (((size_t)(tlb * 4 + tp) * 8 + g) * 16 + row) * 256 + ks * 32;
#pragma unroll
        for (int j = 0; j < 32; ++j) a_lds[tp][ks * 32 + j][row] = src[j];
    }
    __syncthreads();

    int w = tid >> 6, lane = tid & 63;
    int lcol = lane & 15, rq = lane >> 4;
    int cols[8];
    float bs[8];
#pragma unroll
    for (int n = 0; n < 8; ++n) {
        cols[n] = col0_of(w, n) + lcol;
        bs[n] = bias[cols[n]];
    }
    float acc[4][8][4];
#pragma unroll
    for (int tp = 0; tp < 4; ++tp)
#pragma unroll
        for (int n = 0; n < 8; ++n)
#pragma unroll
            for (int r = 0; r < 4; ++r) acc[tp][n][r] = 0.0f;

#pragma unroll 2
    for (int k = 0; k < K; ++k) {
        float bv[8];
#pragma unroll
        for (int n = 0; n < 8; ++n) bv[n] = W[(size_t)k * 1024 + cols[n]];
#pragma unroll
        for (int tp = 0; tp < 4; ++tp) {
            f32x4 av = *(const f32x4*)&a_lds[tp][k][rq * 4];
#pragma unroll
            for (int n = 0; n < 8; ++n)
#pragma unroll
                for (int r = 0; r < 4; ++r) acc[tp][n][r] += av[r] * bv[n];
        }
    }

#pragma unroll
    for (int tp = 0; tp < 4; ++tp) {
        int tl = tlb * 4 + tp;
        size_t base = (((size_t)tl * 8 + g) * 8 + w) * 8 * 64;
#pragma unroll
        for (int n = 0; n < 8; ++n) {
            f32x4 v;
#pragma unroll
            for (int r = 0; r < 4; ++r) v[r] = acc[tp][n][r] + bs[n];
            xw[base + n * 64 + (lcol + 16 * rq)] = v;
        }
    }
}

// ---------------------------------------------------------------------------
// REC: persistent LSTM recurrence over TC steps. 8 blocks (one per 16-row
// batch group) x 512 threads (8 waves). U fp16 resident: tiles 0..5 in VGPRs,
// tiles 6..7 in LDS. h fp16 (swizzled) + c fp32 in LDS.
// ---------------------------------------------------------------------------
__global__ __launch_bounds__(512, 2)
void rec_kernel(const f32x4* __restrict__ xw,    // [TC][8][8][8][64] f32x4
                const half8* __restrict__ Uf,    // [8][8][8][64] half8
                float* __restrict__ h1out,       // [TC][8][16][256] f32 (if writeH)
                _Float16* __restrict__ state_h,  // [8][4096] raw lds image
                float* __restrict__ state_c,     // [8][4096]
                int TC, int first, int writeH) {
    __shared__ half8 u_lds[8192];       // 128 KB: [w][nl(2)][kk(8)][l(64)]
    __shared__ _Float16 h_lds[4096];    // 8 KB, [16][256] XOR-swizzled
    __shared__ float c_lds[4096];       // 16 KB, [16][256]

    int g = blockIdx.x;
    int tid = threadIdx.x;
    int w = tid >> 6, l = tid & 63;
    int lrow = l & 15, lk = l >> 4;

    const half8* ufw = Uf + (size_t)w * 4096;  // [n][kk][l]

    // U register tiles 0..5
    half8 ur[6][8];
#pragma unroll
    for (int n = 0; n < 6; ++n)
#pragma unroll
        for (int kk = 0; kk < 8; ++kk) ur[n][kk] = ufw[(n * 8 + kk) * 64 + l];

    // U LDS tiles 6,7
    for (int nl = 0; nl < 2; ++nl)
        for (int kk = 0; kk < 8; ++kk)
            u_lds[(w * 2 + nl) * 512 + kk * 64 + l] = ufw[((6 + nl) * 8 + kk) * 64 + l];

    // state init
    if (first) {
        for (int i = tid; i < 4096; i += TPB) {
            h_lds[i] = (_Float16)0.0f;
            c_lds[i] = 0.0f;
        }
    } else {
        for (int i = tid; i < 4096; i += TPB) {
            h_lds[i] = state_h[(size_t)g * 4096 + i];
            c_lds[i] = state_c[(size_t)g * 4096 + i];
        }
    }
    __syncthreads();

    for (int t = 0; t < TC; ++t) {
        const f32x4* xwt = xw + (((size_t)t * 8 + g) * 8 + w) * 8 * 64;
        f32x4 acc[8];
#pragma unroll
        for (int n = 0; n < 8; ++n) acc[n] = xwt[n * 64 + l];  // global dwordx4 (xw + bias)

#pragma unroll
        for (int kk = 0; kk < 8; ++kk) {
            int abyte = (lrow * 512 + kk * 64 + lk * 16) ^ ((lrow & 7) << 4);
            half8 af = *(const half8*)((const char*)h_lds + abyte);
#pragma unroll
            for (int n = 0; n < 6; ++n)
                acc[n] = __builtin_amdgcn_mfma_f32_16x16x32_f16(af, ur[n][kk], acc[n], 0, 0, 0);
            acc[6] = __builtin_amdgcn_mfma_f32_16x16x32_f16(af, u_lds[(w * 2 + 0) * 512 + kk * 64 + l], acc[6], 0, 0, 0);
            acc[7] = __builtin_amdgcn_mfma_f32_16x16x32_f16(af, u_lds[(w * 2 + 1) * 512 + kk * 64 + l], acc[7], 0, 0, 0);
        }
        __syncthreads();  // all h_lds reads complete

        // activations; lane owns rows lk*4+r, h-indices j = 32w+16s+lrow
#pragma unroll
        for (int s = 0; s < 2; ++s) {
            f32x4 iv = acc[0 + s], fv = acc[2 + s], gv = acc[4 + s], ov = acc[6 + s];
            int j = 32 * w + 16 * s + lrow;
#pragma unroll
            for (int r = 0; r < 4; ++r) {
                int row = lk * 4 + r;
                float ii = sigmoidf_(iv[r]);
                float ff = sigmoidf_(fv[r]);
                float gg = tanhf_(gv[r]);
                float oo = sigmoidf_(ov[r]);
                float c = ff * c_lds[row * 256 + j] + ii * gg;
                c_lds[row * 256 + j] = c;
                float h = oo * tanhf_(c);
                int hbyte = (row * 512 + j * 2) ^ ((row & 7) << 4);
                *(_Float16*)((char*)h_lds + hbyte) = (_Float16)h;
                if (writeH) h1out[(((size_t)t * 8 + g) * 16 + row) * 256 + j] = h;
            }
        }
        __syncthreads();
    }

    // save state (raw images, swizzle-consistent)
    for (int i = tid; i < 4096; i += TPB) {
        state_h[(size_t)g * 4096 + i] = h_lds[i];
        state_c[(size_t)g * 4096 + i] = c_lds[i];
    }
}

// ---------------------------------------------------------------------------
// DENSE head: out[row] = relu(relu(h2 @ Wd1 + bd1) @ Wd2 + bd2)
// ---------------------------------------------------------------------------
__global__ void dense_kernel(const float* __restrict__ h2, const float* __restrict__ Wd1,
                             const float* __restrict__ bd1, const float* __restrict__ Wd2,
                             const float* __restrict__ bd2, float* __restrict__ out) {
    __shared__ float hrow[256];
    __shared__ float red[128];
    int row = blockIdx.x;
    int tid = threadIdx.x;  // 128
    hrow[tid] = h2[(size_t)row * 256 + tid];
    hrow[tid + 128] = h2[(size_t)row * 256 + tid + 128];
    __syncthreads();
    float a = 0.0f;
    for (int k = 0; k < 256; ++k) a += hrow[k] * Wd1[k * 128 + tid];
    a = fmaxf(a + bd1[tid], 0.0f);
    red[tid] = a * Wd2[tid];
    __syncthreads();
    for (int s = 64; s > 0; s >>= 1) {
        if (tid < s) red[tid] += red[tid + s];
        __syncthreads();
    }
    if (tid == 0) out[row] = fmaxf(red[0] + bd2[0], 0.0f);
}

// ---------------------------------------------------------------------------
extern "C" void kernel_launch(void* const* d_in, const int* in_sizes, int n_in,
                              void* d_out, int out_size, void* d_ws, size_t ws_size,
                              hipStream_t stream) {
    const float* x   = (const float*)d_in[0];
    const float* W1  = (const float*)d_in[1];
    const float* U1  = (const float*)d_in[2];
    const float* b1  = (const float*)d_in[3];
    const float* W2  = (const float*)d_in[4];
    const float* U2  = (const float*)d_in[5];
    const float* b2  = (const float*)d_in[6];
    const float* Wd1 = (const float*)d_in[7];
    const float* bd1 = (const float*)d_in[8];
    const float* Wd2 = (const float*)d_in[9];
    const float* bd2 = (const float*)d_in[10];
    float* out = (float*)d_out;

    char* ws = (char*)d_ws;
    size_t off = 0;
    auto alloc = [&](size_t bytes) -> char* {
        char* p = ws + off;
        off = (off + bytes + 1023) & ~(size_t)1023;
        return p;
    };
    half8* U1f    = (half8*)alloc(32768 * 16);
    half8* U2f    = (half8*)alloc(32768 * 16);
    _Float16* s1h = (_Float16*)alloc(8 * 4096 * 2);
    float* s1c    = (float*)alloc(8 * 4096 * 4);
    _Float16* s2h = (_Float16*)alloc(8 * 4096 * 2);
    float* s2c    = (float*)alloc(8 * 4096 * 4);
    size_t fixed = off;

    int TC = 256;
    while (TC > 4 && fixed + (size_t)TC * (512 + 128) * 1024 + 8192 > ws_size) TC >>= 1;
    f32x4* xwb = (f32x4*)alloc((size_t)TC * 32768 * 16);
    float* h1c = (float*)alloc((size_t)TC * 32768 * 4);
    int chunks = 1024 / TC;

    prep_kernel<<<dim3(64), dim3(512), 0, stream>>>(U1, U2, U1f, U2f);

    for (int c = 0; c < chunks; ++c) {
        gemm_xw<128><<<dim3((TC / 4) * 8), dim3(512), 0, stream>>>(x, W1, b1, xwb, c * TC);
        rec_kernel<<<dim3(8), dim3(512), 0, stream>>>(xwb, U1f, h1c, s1h, s1c, TC, (c == 0) ? 1 : 0, 1);
        gemm_xw<256><<<dim3((TC / 4) * 8), dim3(512), 0, stream>>>(h1c, W2, b2, xwb, 0);
        rec_kernel<<<dim3(8), dim3(512), 0, stream>>>(xwb, U2f, h1c, s2h, s2c, TC, (c == 0) ? 1 : 0,
                                                      (c == chunks - 1) ? 1 : 0);
    }

    dense_kernel<<<dim3(128), dim3(128), 0, stream>>>(h1c + (size_t)(TC - 1) * 32768, Wd1, bd1, Wd2,
                                                      bd2, out);
}

// Round 2
// 10809.173 us; speedup vs baseline: 1.0427x; 1.0427x over previous
//
#include <hip/hip_runtime.h>

typedef _Float16 half8 __attribute__((ext_vector_type(8)));
typedef float f32x4 __attribute__((ext_vector_type(4)));

__device__ __forceinline__ float sigmoidf_(float x) { return 1.0f / (1.0f + __expf(-x)); }
__device__ __forceinline__ float tanhf_(float x) {
    // tanh(x) = 1 - 2/(1+e^{2x}); robust for large |x|
    return 1.0f - 2.0f / (1.0f + __expf(2.0f * x));
}

// Column of the gate matrix owned by (wave w, tile n, lane-col lc):
// gate q = n>>1, sub-tile s = n&1, h-index j = 32w + 16s + lc
__device__ __forceinline__ int col0_of(int w, int n) {
    return 256 * (n >> 1) + 32 * w + 16 * (n & 1);
}

// ---------------------------------------------------------------------------
// PREP: f16 B-fragment tables for U1,U2,W2 (K=256) and W1 (K=128).
// Layout: F[w][n][kk][lane] half8, b[j] = M[kk*32+(l>>4)*8+j][col0_of(w,n)+(l&15)]
// ---------------------------------------------------------------------------
__global__ void prep_kernel(const float* __restrict__ U1, const float* __restrict__ U2,
                            const float* __restrict__ W1, const float* __restrict__ W2,
                            half8* __restrict__ U1f, half8* __restrict__ U2f,
                            half8* __restrict__ W1f, half8* __restrict__ W2f) {
    int id = blockIdx.x * 512 + threadIdx.x;  // 0..32767
    int l = id & 63;
    {
        int kk = (id >> 6) & 7, n = (id >> 9) & 7, w = (id >> 12) & 7;
        int col = col0_of(w, n) + (l & 15);
        int k0 = kk * 32 + (l >> 4) * 8;
        half8 a, b, d;
#pragma unroll
        for (int j = 0; j < 8; ++j) {
            a[j] = (_Float16)U1[(k0 + j) * 1024 + col];
            b[j] = (_Float16)U2[(k0 + j) * 1024 + col];
            d[j] = (_Float16)W2[(k0 + j) * 1024 + col];
        }
        U1f[id] = a; U2f[id] = b; W2f[id] = d;
    }
    if (id < 16384) {  // W1: K=128 -> KK=4
        int kk = (id >> 6) & 3, n = (id >> 8) & 7, w = (id >> 11) & 7;
        int col = col0_of(w, n) + (l & 15);
        int k0 = kk * 32 + (l >> 4) * 8;
        half8 d;
#pragma unroll
        for (int j = 0; j < 8; ++j) d[j] = (_Float16)W1[(k0 + j) * 1024 + col];
        W1f[id] = d;
    }
}

// ---------------------------------------------------------------------------
// GEMM_XW (f16 MFMA, f32 accumulate): xw[tl][g][w][n][lane] f32x4 (C-frag layout)
// 4 timesteps per block (W fragments reused). A staged in LDS f16, XOR-swizzled.
//   K=128: A = x[16g+row][t][f] (f32 -> f16)
//   K=256: A = h1c[tl][g][row][j] (f16)
// ---------------------------------------------------------------------------
template <int K>
__global__ __launch_bounds__(512, 1)
void gemm_xw(const void* __restrict__ Ain, const half8* __restrict__ Wf,
             const float* __restrict__ bias, f32x4* __restrict__ xw, int t0) {
    constexpr int KBLK = K / 8, KK = K / 32;
    __shared__ _Float16 a_lds[4 * 16 * K];
    int bid = blockIdx.x, tlb = bid >> 3, g = bid & 7, tid = threadIdx.x;

    for (int idx = tid; idx < 4 * 16 * KBLK; idx += 512) {
        int tq = idx / (16 * KBLK), rem = idx % (16 * KBLK);
        int row = rem / KBLK, kb = rem % KBLK;
        half8 hv;
        if constexpr (K == 128) {
            const float* src = (const float*)Ain +
                ((size_t)(16 * g + row) * 1024 + (size_t)(t0 + tlb * 4 + tq)) * 128 + kb * 8;
            f32x4 p0 = *(const f32x4*)src, p1 = *(const f32x4*)(src + 4);
#pragma unroll
            for (int j = 0; j < 4; ++j) { hv[j] = (_Float16)p0[j]; hv[4 + j] = (_Float16)p1[j]; }
        } else {
            const _Float16* src = (const _Float16*)Ain +
                (((size_t)(tlb * 4 + tq) * 8 + g) * 16 + row) * 256 + kb * 8;
            hv = *(const half8*)src;
        }
        *(half8*)((char*)a_lds + (size_t)tq * 16 * K * 2 + row * K * 2 +
                  ((kb ^ ((row >> 2) << 1)) << 4)) = hv;
    }
    __syncthreads();

    int w = tid >> 6, l = tid & 63, lrow = l & 15, lk = l >> 4;
    float bs[8];
#pragma unroll
    for (int n = 0; n < 8; ++n) bs[n] = bias[col0_of(w, n) + lrow];
    f32x4 acc[4][8];
#pragma unroll
    for (int tq = 0; tq < 4; ++tq)
#pragma unroll
        for (int n = 0; n < 8; ++n) acc[tq][n] = f32x4{bs[n], bs[n], bs[n], bs[n]};

#pragma unroll
    for (int kk = 0; kk < KK; ++kk) {
        half8 bf[8];
#pragma unroll
        for (int n = 0; n < 8; ++n) bf[n] = Wf[((w * 8 + n) * KK + kk) * 64 + l];
#pragma unroll
        for (int tq = 0; tq < 4; ++tq) {
            half8 af = *(const half8*)((char*)a_lds + (size_t)tq * 16 * K * 2 + lrow * K * 2 +
                                       (((kk * 4 + lk) ^ ((lrow >> 2) << 1)) << 4));
#pragma unroll
            for (int n = 0; n < 8; ++n)
                acc[tq][n] = __builtin_amdgcn_mfma_f32_16x16x32_f16(af, bf[n], acc[tq][n], 0, 0, 0);
        }
    }
#pragma unroll
    for (int tq = 0; tq < 4; ++tq) {
        size_t base = (((size_t)(tlb * 4 + tq) * 8 + g) * 8 + w) * 512;
#pragma unroll
        for (int n = 0; n < 8; ++n) xw[base + n * 64 + l] = acc[tq][n];
    }
}

// ---------------------------------------------------------------------------
// REC: persistent LSTM recurrence. 8 blocks x 512 threads (8 waves, 1/CU).
// U f16: tiles 0..4 in VGPRs, 5..6 in LDS, 7 streamed from L2.
// h f16 double-buffered LDS (XOR-swizzled); c in registers.
// One raw s_barrier per step (lgkmcnt only); xw[t+1] prefetched into acc regs.
// ---------------------------------------------------------------------------
__global__ __launch_bounds__(512, 1)
void rec_kernel(const f32x4* __restrict__ xw,    // [TC][8][8][8][64] f32x4
                const half8* __restrict__ Uf,    // [8][8][8][64] half8
                _Float16* __restrict__ h1out,    // [TC][8][16][256] f16 (if writeH)
                _Float16* __restrict__ state_h,  // [8][4096] raw swizzled image
                float* __restrict__ state_c,     // [8][512][8]
                int TC, int first, int writeH) {
    __shared__ half8 u_lds[8192];        // 128 KB: [w][slot(2)][kk(8)][l(64)]
    __shared__ _Float16 h_lds[2][4096];  // 2 x 8 KB, swizzled [16][256]

    int g = blockIdx.x, tid = threadIdx.x, w = tid >> 6, l = tid & 63;
    int lrow = l & 15, lk = l >> 4;

    const half8* ufw = Uf + (size_t)w * 4096;  // [n][kk][l]

    half8 ur[5][8];  // tiles 0..4 resident (160 VGPRs)
#pragma unroll
    for (int n = 0; n < 5; ++n)
#pragma unroll
        for (int kk = 0; kk < 8; ++kk) ur[n][kk] = ufw[(n * 8 + kk) * 64 + l];

    for (int slot = 0; slot < 2; ++slot)  // tiles 5,6 -> LDS
        for (int kk = 0; kk < 8; ++kk)
            u_lds[(w * 2 + slot) * 512 + kk * 64 + l] = ufw[((5 + slot) * 8 + kk) * 64 + l];
    const half8* uS = ufw + 3584;  // tile 7 streamed (stays L2-hot)

    float c[8];
    if (first) {
        for (int i = tid; i < 4096; i += 512) h_lds[0][i] = (_Float16)0.0f;
#pragma unroll
        for (int i = 0; i < 8; ++i) c[i] = 0.0f;
    } else {
        for (int i = tid; i < 4096; i += 512) h_lds[0][i] = state_h[(size_t)g * 4096 + i];
        const f32x4* cs = (const f32x4*)(state_c + ((size_t)g * 512 + tid) * 8);
        f32x4 c0 = cs[0], c1 = cs[1];
#pragma unroll
        for (int i = 0; i < 4; ++i) { c[i] = c0[i]; c[4 + i] = c1[i]; }
    }

    f32x4 acc[8];
    {
        const f32x4* xw0 = xw + ((size_t)g * 8 + w) * 512;
#pragma unroll
        for (int n = 0; n < 8; ++n) acc[n] = xw0[n * 64 + l];
    }
    __syncthreads();

#define ACT(s, r)                                                                     \
    {                                                                                 \
        float ii = sigmoidf_(acc[0 + (s)][r]);                                        \
        float ff = sigmoidf_(acc[2 + (s)][r]);                                        \
        float gg = tanhf_(acc[4 + (s)][r]);                                           \
        float oo = sigmoidf_(acc[6 + (s)][r]);                                        \
        float cn = ff * c[(s) * 4 + (r)] + ii * gg;                                   \
        c[(s) * 4 + (r)] = cn;                                                        \
        float hf = oo * tanhf_(cn);                                                   \
        int j = 32 * w + 16 * (s) + lrow;                                             \
        int row = lk * 4 + (r);                                                       \
        *(_Float16*)(hn + row * 512 + (((j >> 3) ^ (lk << 1)) << 4) + (j & 7) * 2) =  \
            (_Float16)hf;                                                             \
        if (writeH) h1out[(((size_t)t * 8 + g) * 16 + row) * 256 + j] = (_Float16)hf; \
    }

    for (int t = 0; t < TC; ++t) {
        const char* hb = (const char*)h_lds[t & 1];
        char* hn = (char*)h_lds[(t + 1) & 1];
        half8 sfa = uS[0 * 64 + l], sfb = uS[1 * 64 + l];  // stream lookahead-2

        // PASS 1: even tiles {0,2,4,6} = gates(i,f,g,o) sub-tile s=0
#pragma unroll
        for (int kk = 0; kk < 8; ++kk) {
            half8 af = *(const half8*)(hb + lrow * 512 +
                                       (((kk * 4 + lk) ^ ((lrow >> 2) << 1)) << 4));
            acc[0] = __builtin_amdgcn_mfma_f32_16x16x32_f16(af, ur[0][kk], acc[0], 0, 0, 0);
            acc[2] = __builtin_amdgcn_mfma_f32_16x16x32_f16(af, ur[2][kk], acc[2], 0, 0, 0);
            acc[4] = __builtin_amdgcn_mfma_f32_16x16x32_f16(af, ur[4][kk], acc[4], 0, 0, 0);
            acc[6] = __builtin_amdgcn_mfma_f32_16x16x32_f16(
                af, u_lds[(w * 2 + 1) * 512 + kk * 64 + l], acc[6], 0, 0, 0);
        }
        // PASS 2: odd tiles {1,3,5,7}; activation of s=0 interleaved
#pragma unroll
        for (int kk = 0; kk < 8; ++kk) {
            half8 af = *(const half8*)(hb + lrow * 512 +
                                       (((kk * 4 + lk) ^ ((lrow >> 2) << 1)) << 4));
            half8 sfc = sfb;
            if (kk < 6) sfc = uS[(kk + 2) * 64 + l];
            acc[1] = __builtin_amdgcn_mfma_f32_16x16x32_f16(af, ur[1][kk], acc[1], 0, 0, 0);
            acc[3] = __builtin_amdgcn_mfma_f32_16x16x32_f16(af, ur[3][kk], acc[3], 0, 0, 0);
            acc[5] = __builtin_amdgcn_mfma_f32_16x16x32_f16(
                af, u_lds[(w * 2 + 0) * 512 + kk * 64 + l], acc[5], 0, 0, 0);
            acc[7] = __builtin_amdgcn_mfma_f32_16x16x32_f16(af, sfa, acc[7], 0, 0, 0);
            sfa = sfb; sfb = sfc;
            if (kk == 4) ACT(0, 0);
            if (kk == 5) ACT(0, 1);
            if (kk == 6) ACT(0, 2);
            if (kk == 7) ACT(0, 3);
        }
        // prefetch xw[t+1] for even tiles (acc evens consumed by ACT(0,*))
        int tn = (t + 1 < TC) ? t + 1 : t;
        const f32x4* xwn = xw + (((size_t)tn * 8 + g) * 8 + w) * 512;
        acc[0] = xwn[0 * 64 + l]; acc[2] = xwn[2 * 64 + l];
        acc[4] = xwn[4 * 64 + l]; acc[6] = xwn[6 * 64 + l];
        ACT(1, 0); ACT(1, 1); ACT(1, 2); ACT(1, 3);
        acc[1] = xwn[1 * 64 + l]; acc[3] = xwn[3 * 64 + l];
        acc[5] = xwn[5 * 64 + l]; acc[7] = xwn[7 * 64 + l];
        // barrier: drain LDS ops only; global loads/stores stay in flight
        asm volatile("s_waitcnt lgkmcnt(0)" ::: "memory");
        __builtin_amdgcn_s_barrier();
        __builtin_amdgcn_sched_barrier(0);
    }
#undef ACT

    // save state (TC even -> final h image in buffer 0)
    for (int i = tid; i < 4096; i += 512) state_h[(size_t)g * 4096 + i] = h_lds[0][i];
    f32x4 c0, c1;
#pragma unroll
    for (int i = 0; i < 4; ++i) { c0[i] = c[i]; c1[i] = c[4 + i]; }
    f32x4* cs = (f32x4*)(state_c + ((size_t)g * 512 + tid) * 8);
    cs[0] = c0; cs[1] = c1;
}

// ---------------------------------------------------------------------------
// DENSE head: out[b] = relu(relu(h2 @ Wd1 + bd1) @ Wd2 + bd2); h2 is f16
// ---------------------------------------------------------------------------
__global__ void dense_kernel(const _Float16* __restrict__ h2, const float* __restrict__ Wd1,
                             const float* __restrict__ bd1, const float* __restrict__ Wd2,
                             const float* __restrict__ bd2, float* __restrict__ out) {
    __shared__ float hrow[256];
    __shared__ float red[128];
    int rg = blockIdx.x;  // batch row 0..127; g = rg>>4, row = rg&15
    int g = rg >> 4, row = rg & 15;
    int tid = threadIdx.x;  // 128
    hrow[tid] = (float)h2[((size_t)g * 16 + row) * 256 + tid];
    hrow[tid + 128] = (float)h2[((size_t)g * 16 + row) * 256 + tid + 128];
    __syncthreads();
    float a = 0.0f;
    for (int k = 0; k < 256; ++k) a += hrow[k] * Wd1[k * 128 + tid];
    a = fmaxf(a + bd1[tid], 0.0f);
    red[tid] = a * Wd2[tid];
    __syncthreads();
    for (int s = 64; s > 0; s >>= 1) {
        if (tid < s) red[tid] += red[tid + s];
        __syncthreads();
    }
    if (tid == 0) out[rg] = fmaxf(red[0] + bd2[0], 0.0f);
}

// ---------------------------------------------------------------------------
extern "C" void kernel_launch(void* const* d_in, const int* in_sizes, int n_in,
                              void* d_out, int out_size, void* d_ws, size_t ws_size,
                              hipStream_t stream) {
    const float* x   = (const float*)d_in[0];
    const float* W1  = (const float*)d_in[1];
    const float* U1  = (const float*)d_in[2];
    const float* b1  = (const float*)d_in[3];
    const float* W2  = (const float*)d_in[4];
    const float* U2  = (const float*)d_in[5];
    const float* b2  = (const float*)d_in[6];
    const float* Wd1 = (const float*)d_in[7];
    const float* bd1 = (const float*)d_in[8];
    const float* Wd2 = (const float*)d_in[9];
    const float* bd2 = (const float*)d_in[10];
    float* out = (float*)d_out;

    char* ws = (char*)d_ws;
    size_t off = 0;
    auto alloc = [&](size_t bytes) -> char* {
        char* p = ws + off;
        off = (off + bytes + 1023) & ~(size_t)1023;
        return p;
    };
    half8* U1f    = (half8*)alloc(32768 * 16);
    half8* U2f    = (half8*)alloc(32768 * 16);
    half8* W1f    = (half8*)alloc(16384 * 16);
    half8* W2f    = (half8*)alloc(32768 * 16);
    _Float16* s1h = (_Float16*)alloc(8 * 4096 * 2);
    float* s1c    = (float*)alloc(8 * 512 * 8 * 4);
    _Float16* s2h = (_Float16*)alloc(8 * 4096 * 2);
    float* s2c    = (float*)alloc(8 * 512 * 8 * 4);
    size_t fixed = off;

    int TC = 256;
    while (TC > 4 && fixed + (size_t)TC * (512 + 64) * 1024 + 65536 > ws_size) TC >>= 1;
    f32x4* xwb    = (f32x4*)alloc((size_t)TC * 32768 * 16);
    _Float16* h1c = (_Float16*)alloc((size_t)TC * 32768 * 2);
    int chunks = 1024 / TC;

    prep_kernel<<<dim3(64), dim3(512), 0, stream>>>(U1, U2, W1, W2, U1f, U2f, W1f, W2f);

    for (int c = 0; c < chunks; ++c) {
        gemm_xw<128><<<dim3((TC / 4) * 8), dim3(512), 0, stream>>>(x, W1f, b1, xwb, c * TC);
        rec_kernel<<<dim3(8), dim3(512), 0, stream>>>(xwb, U1f, h1c, s1h, s1c, TC,
                                                      (c == 0) ? 1 : 0, 1);
        gemm_xw<256><<<dim3((TC / 4) * 8), dim3(512), 0, stream>>>(h1c, W2f, b2, xwb, 0);
        rec_kernel<<<dim3(8), dim3(512), 0, stream>>>(xwb, U2f, h1c, s2h, s2c, TC,
                                                      (c == 0) ? 1 : 0, (c == chunks - 1) ? 1 : 0);
    }

    dense_kernel<<<dim3(128), dim3(128), 0, stream>>>(h1c + (size_t)(TC - 1) * 32768, Wd1, bd1,
                                                      Wd2, bd2, out);
}